// Round 1
// baseline (62.887 us; speedup 1.0000x reference)
//
#include <hip/hip_runtime.h>
#include <math.h>

// Chamfer distance, N=2, D=3 fp32.
// Pass 1: per-(query, target-segment) partial min via LDS-staged target tiles,
//         combined with deterministic uint atomicMin (flip-key encoding).
// Pass 2a: per-chunk deterministic tree-reduction of decoded mins -> partial sums.
// Pass 2b: tiny kernel combines partials into out[n] = mean1 + mean2.

#define BLOCK 256
#define QPT 2            // query points per thread
#define SEG 512          // target points per segment (LDS tile, 8 KB)
#define P2A_BLOCKS 6     // reduction blocks per z-slice
#define P2A_PAD 8

// Order-preserving float->uint key: uint compare == float compare (all finite values).
__device__ __forceinline__ unsigned fkey(float f) {
    unsigned u = __float_as_uint(f);
    unsigned mask = (unsigned)((int)u >> 31) | 0x80000000u;
    return u ^ mask;
}
__device__ __forceinline__ float fdec(unsigned k) {
    unsigned mask = (k & 0x80000000u) ? 0x80000000u : 0xFFFFFFFFu;
    return __uint_as_float(k ^ mask);
}

__global__ __launch_bounds__(BLOCK) void chamfer_pass1(
    const float* __restrict__ c1, const float* __restrict__ c2,
    int P1, int P2, unsigned* __restrict__ mk_all) {
    const int z   = blockIdx.z;        // n*2 + dir
    const int n   = z >> 1;
    const int dir = z & 1;
    const int Pq = dir ? P2 : P1;
    const int Pt = dir ? P1 : P2;
    const float* Q = (dir ? c2 : c1) + (size_t)n * Pq * 3;
    const float* T = (dir ? c1 : c2) + (size_t)n * Pt * 3;
    unsigned* mk = mk_all + (size_t)n * (P1 + P2) + (dir ? P1 : 0);

    // Stage target tile as (-2x, -2y, -2z, |b|^2); pad with +INF sentinel.
    __shared__ float4 tile[SEG];
    const int t0 = blockIdx.y * SEG;
    const int nt = Pt - t0;            // valid targets in this segment (may be <0)
    for (int j = threadIdx.x; j < SEG; j += BLOCK) {
        float4 v;
        if (j < nt) {
            const float* p = T + (size_t)(t0 + j) * 3;
            float x = p[0], y = p[1], w = p[2];
            v = make_float4(-2.f * x, -2.f * y, -2.f * w,
                            fmaf(x, x, fmaf(y, y, w * w)));
        } else {
            v = make_float4(0.f, 0.f, 0.f, INFINITY);
        }
        tile[j] = v;
    }
    __syncthreads();

    const int qi0 = blockIdx.x * (BLOCK * QPT) + threadIdx.x;
    const int qi1 = qi0 + BLOCK;
    float ax0 = 0.f, ay0 = 0.f, az0 = 0.f;
    float ax1 = 0.f, ay1 = 0.f, az1 = 0.f;
    if (qi0 < Pq) { const float* p = Q + (size_t)qi0 * 3; ax0 = p[0]; ay0 = p[1]; az0 = p[2]; }
    if (qi1 < Pq) { const float* p = Q + (size_t)qi1 * 3; ax1 = p[0]; ay1 = p[1]; az1 = p[2]; }

    float m0 = INFINITY, m1 = INFINITY;
    #pragma unroll 8
    for (int j = 0; j < SEG; ++j) {
        float4 b = tile[j];   // uniform address -> ds_read_b128 broadcast
        m0 = fminf(m0, fmaf(ax0, b.x, fmaf(ay0, b.y, fmaf(az0, b.z, b.w))));
        m1 = fminf(m1, fmaf(ax1, b.x, fmaf(ay1, b.y, fmaf(az1, b.z, b.w))));
    }

    // min_j ||a-b||^2 = ||a||^2 + min_j(||b||^2 - 2 a.b); atomicMin is order-independent.
    if (qi0 < Pq)
        atomicMin(&mk[qi0], fkey(fmaf(ax0, ax0, fmaf(ay0, ay0, az0 * az0)) + m0));
    if (qi1 < Pq)
        atomicMin(&mk[qi1], fkey(fmaf(ax1, ax1, fmaf(ay1, ay1, az1 * az1)) + m1));
}

__global__ __launch_bounds__(256) void chamfer_pass2a(
    const unsigned* __restrict__ mk_all, int P1, int P2,
    float* __restrict__ partial) {
    const int z = blockIdx.y;          // 0..3
    const int b = blockIdx.x;          // 0..P2A_BLOCKS-1
    const int n = z >> 1, dir = z & 1;
    const int Pq = dir ? P2 : P1;
    const unsigned* mk = mk_all + (size_t)n * (P1 + P2) + (dir ? P1 : 0);
    const int span = (Pq + P2A_BLOCKS - 1) / P2A_BLOCKS;
    const int lo = b * span;
    const int hi = min(lo + span, Pq);
    float s = 0.f;
    for (int q = lo + threadIdx.x; q < hi; q += 256)
        s += fdec(mk[q]);
    __shared__ float red[256];
    red[threadIdx.x] = s;
    __syncthreads();
    for (int off = 128; off > 0; off >>= 1) {
        if (threadIdx.x < off) red[threadIdx.x] += red[threadIdx.x + off];
        __syncthreads();
    }
    if (threadIdx.x == 0) partial[z * P2A_PAD + b] = red[0];
}

__global__ void chamfer_pass2b(const float* __restrict__ partial,
                               int P1, int P2, float* __restrict__ out) {
    int n = threadIdx.x;
    if (n < 2) {
        float sA = 0.f, sB = 0.f;
        for (int b = 0; b < P2A_BLOCKS; ++b) {
            sA += partial[(n * 2 + 0) * P2A_PAD + b];
            sB += partial[(n * 2 + 1) * P2A_PAD + b];
        }
        out[n] = sA / (float)P1 + sB / (float)P2;
    }
}

extern "C" void kernel_launch(void* const* d_in, const int* in_sizes, int n_in,
                              void* d_out, int out_size, void* d_ws, size_t ws_size,
                              hipStream_t stream) {
    const float* c1 = (const float*)d_in[0];
    const float* c2 = (const float*)d_in[1];
    const int N  = 2;
    const int P1 = in_sizes[0] / (N * 3);
    const int P2 = in_sizes[1] / (N * 3);

    unsigned* mk = (unsigned*)d_ws;
    size_t mk_bytes = (size_t)N * (P1 + P2) * sizeof(unsigned);
    float* partial = (float*)((char*)d_ws + ((mk_bytes + 255) & ~(size_t)255));

    // Re-init min keys every call: 0xFFFFFFFF > any encoded key.
    hipMemsetAsync(d_ws, 0xFF, mk_bytes, stream);

    const int Pqmax = P1 > P2 ? P1 : P2;
    const int Ptmax = Pqmax;
    dim3 g1((Pqmax + BLOCK * QPT - 1) / (BLOCK * QPT),
            (Ptmax + SEG - 1) / SEG,
            2 * N);
    chamfer_pass1<<<g1, BLOCK, 0, stream>>>(c1, c2, P1, P2, mk);

    dim3 g2(P2A_BLOCKS, 2 * N);
    chamfer_pass2a<<<g2, 256, 0, stream>>>(mk, P1, P2, partial);

    chamfer_pass2b<<<1, 64, 0, stream>>>(partial, P1, P2, (float*)d_out);
}

// Round 2
// 58.793 us; speedup vs baseline: 1.0696x; 1.0696x over previous
//
#include <hip/hip_runtime.h>
#include <math.h>

// Chamfer distance, N=2, D=3 fp32.
// Pass 1: per-(query, target-segment) partial min via LDS-staged target tiles,
//         combined with deterministic uint atomicMin (flip-key encoding).
//         QPT=4 queries/thread, 2 targets/step, v_min3 fusion.
// Pass 2a: per-chunk deterministic tree-reduction of decoded mins -> partial sums.
// Pass 2b: tiny kernel combines partials into out[n] = mean1 + mean2.

#define BLOCK 256
#define QPT 4            // query points per thread
#define SEG 384          // target points per segment (LDS tile, 6 KB) -> grid 12x32x4 = 1536 = 6/CU
#define P2A_BLOCKS 6     // reduction blocks per z-slice
#define P2A_PAD 8

// Order-preserving float->uint key: uint compare == float compare (all finite values).
__device__ __forceinline__ unsigned fkey(float f) {
    unsigned u = __float_as_uint(f);
    unsigned mask = (unsigned)((int)u >> 31) | 0x80000000u;
    return u ^ mask;
}
__device__ __forceinline__ float fdec(unsigned k) {
    unsigned mask = (k & 0x80000000u) ? 0x80000000u : 0xFFFFFFFFu;
    return __uint_as_float(k ^ mask);
}

__global__ __launch_bounds__(BLOCK) void chamfer_pass1(
    const float* __restrict__ c1, const float* __restrict__ c2,
    int P1, int P2, unsigned* __restrict__ mk_all) {
    const int z   = blockIdx.z;        // n*2 + dir
    const int n   = z >> 1;
    const int dir = z & 1;
    const int Pq = dir ? P2 : P1;
    const int Pt = dir ? P1 : P2;
    const float* Q = (dir ? c2 : c1) + (size_t)n * Pq * 3;
    const float* T = (dir ? c1 : c2) + (size_t)n * Pt * 3;
    unsigned* mk = mk_all + (size_t)n * (P1 + P2) + (dir ? P1 : 0);

    // Stage target tile as (-2x, -2y, -2z, |b|^2); pad with +INF sentinel.
    __shared__ float4 tile[SEG];
    const int t0 = blockIdx.y * SEG;
    const int nt = Pt - t0;            // valid targets in this segment (may be <0)
    for (int j = threadIdx.x; j < SEG; j += BLOCK) {
        float4 v;
        if (j < nt) {
            const float* p = T + (size_t)(t0 + j) * 3;
            float x = p[0], y = p[1], w = p[2];
            v = make_float4(-2.f * x, -2.f * y, -2.f * w,
                            fmaf(x, x, fmaf(y, y, w * w)));
        } else {
            v = make_float4(0.f, 0.f, 0.f, INFINITY);
        }
        tile[j] = v;
    }
    __syncthreads();

    const int qbase = blockIdx.x * (BLOCK * QPT) + threadIdx.x;
    float ax[QPT], ay[QPT], az[QPT], sq[QPT], m[QPT];
    #pragma unroll
    for (int k = 0; k < QPT; ++k) {
        const int qi = qbase + k * BLOCK;
        ax[k] = 0.f; ay[k] = 0.f; az[k] = 0.f;
        if (qi < Pq) {
            const float* p = Q + (size_t)qi * 3;
            ax[k] = p[0]; ay[k] = p[1]; az[k] = p[2];
        }
        sq[k] = fmaf(ax[k], ax[k], fmaf(ay[k], ay[k], az[k] * az[k]));
        m[k] = INFINITY;
    }

    #pragma unroll 4
    for (int j = 0; j < SEG; j += 2) {
        float4 b0 = tile[j];       // uniform address -> ds_read_b128 broadcast
        float4 b1 = tile[j + 1];
        #pragma unroll
        for (int k = 0; k < QPT; ++k) {
            float d0 = fmaf(ax[k], b0.x, fmaf(ay[k], b0.y, fmaf(az[k], b0.z, b0.w)));
            float d1 = fmaf(ax[k], b1.x, fmaf(ay[k], b1.y, fmaf(az[k], b1.z, b1.w)));
            m[k] = fminf(fminf(m[k], d0), d1);   // fuses to v_min3_f32
        }
    }

    // min_j ||a-b||^2 = ||a||^2 + min_j(||b||^2 - 2 a.b); atomicMin is order-independent.
    #pragma unroll
    for (int k = 0; k < QPT; ++k) {
        const int qi = qbase + k * BLOCK;
        if (qi < Pq)
            atomicMin(&mk[qi], fkey(sq[k] + m[k]));
    }
}

__global__ __launch_bounds__(256) void chamfer_pass2a(
    const unsigned* __restrict__ mk_all, int P1, int P2,
    float* __restrict__ partial) {
    const int z = blockIdx.y;          // 0..3
    const int b = blockIdx.x;          // 0..P2A_BLOCKS-1
    const int n = z >> 1, dir = z & 1;
    const int Pq = dir ? P2 : P1;
    const unsigned* mk = mk_all + (size_t)n * (P1 + P2) + (dir ? P1 : 0);
    const int span = (Pq + P2A_BLOCKS - 1) / P2A_BLOCKS;
    const int lo = b * span;
    const int hi = min(lo + span, Pq);
    float s = 0.f;
    for (int q = lo + threadIdx.x; q < hi; q += 256)
        s += fdec(mk[q]);
    __shared__ float red[256];
    red[threadIdx.x] = s;
    __syncthreads();
    for (int off = 128; off > 0; off >>= 1) {
        if (threadIdx.x < off) red[threadIdx.x] += red[threadIdx.x + off];
        __syncthreads();
    }
    if (threadIdx.x == 0) partial[z * P2A_PAD + b] = red[0];
}

__global__ void chamfer_pass2b(const float* __restrict__ partial,
                               int P1, int P2, float* __restrict__ out) {
    int n = threadIdx.x;
    if (n < 2) {
        float sA = 0.f, sB = 0.f;
        for (int b = 0; b < P2A_BLOCKS; ++b) {
            sA += partial[(n * 2 + 0) * P2A_PAD + b];
            sB += partial[(n * 2 + 1) * P2A_PAD + b];
        }
        out[n] = sA / (float)P1 + sB / (float)P2;
    }
}

extern "C" void kernel_launch(void* const* d_in, const int* in_sizes, int n_in,
                              void* d_out, int out_size, void* d_ws, size_t ws_size,
                              hipStream_t stream) {
    const float* c1 = (const float*)d_in[0];
    const float* c2 = (const float*)d_in[1];
    const int N  = 2;
    const int P1 = in_sizes[0] / (N * 3);
    const int P2 = in_sizes[1] / (N * 3);

    unsigned* mk = (unsigned*)d_ws;
    size_t mk_bytes = (size_t)N * (P1 + P2) * sizeof(unsigned);
    float* partial = (float*)((char*)d_ws + ((mk_bytes + 255) & ~(size_t)255));

    // Re-init min keys every call: 0xFFFFFFFF > any encoded key.
    hipMemsetAsync(d_ws, 0xFF, mk_bytes, stream);

    const int Pqmax = P1 > P2 ? P1 : P2;
    const int Ptmax = Pqmax;
    dim3 g1((Pqmax + BLOCK * QPT - 1) / (BLOCK * QPT),
            (Ptmax + SEG - 1) / SEG,
            2 * N);
    chamfer_pass1<<<g1, BLOCK, 0, stream>>>(c1, c2, P1, P2, mk);

    dim3 g2(P2A_BLOCKS, 2 * N);
    chamfer_pass2a<<<g2, 256, 0, stream>>>(mk, P1, P2, partial);

    chamfer_pass2b<<<1, 64, 0, stream>>>(partial, P1, P2, (float*)d_out);
}